// Round 6
// baseline (346.646 us; speedup 1.0000x reference)
//
#include <hip/hip_runtime.h>
#include <hip/hip_bf16.h>
#include <math.h>

// Shapes (fixed per reference): B=40, M=8, D=256, H=16x16 -> HW=256, L=15
// Blocks: 8 blocks of 5 samples. Per block: R = 2048 regions, T = 75 tokens.
#define NG 8
#define NB5 5
#define NM 8
#define NHW 256
#define NR 2048
#define ND 256
#define NL 15
#define NT 75
#define NGB 40

// workspace layout (in floats)
#define OFF_S    0                         // s [gb][t][r], aliased later as VTP [gb][m][t][d]
#define SZ_S     (NGB*NT*NR)               // 6,144,000
#define OFF_W    (OFF_S + SZ_S)            // alpha [gb][t][r]
#define OFF_RMAX (OFF_W + SZ_S)            // [gb][seg][r]
#define SZ_RST   (NGB*5*NR)                // 409,600
#define OFF_RSUM (OFF_RMAX + SZ_RST)
#define OFF_SD   (OFF_RSUM + SZ_RST)       // [gb][m][t]
#define SZ_SD    (NGB*NM*NT)
#define OFF_VNS  (OFF_SD + SZ_SD)          // [gb][m][d]
#define SZ_VNS   (NGB*NM*ND)
#define OFF_LG   (OFF_VNS + SZ_VNS)        // logit [gb][t]
#define SZ_LG    (NGB*NT)
#define OFF_LG2  (OFF_LG + SZ_LG)          // logit2 [gb][m][s]
#define SZ_LG2   (NGB*NM*5)
#define OFF_BETA (OFF_LG2 + SZ_LG2)        // [gb][m][t]
#define SZ_BETA  (NGB*NM*NT)
#define OFF_BLK  (OFF_BETA + SZ_BETA)      // [g]

__device__ __forceinline__ float bredsum(float v, float* red) {
    int tid = threadIdx.x;
    red[tid] = v; __syncthreads();
    for (int s2 = 128; s2 > 0; s2 >>= 1) {
        if (tid < s2) red[tid] += red[tid + s2];
        __syncthreads();
    }
    float r = red[0]; __syncthreads();
    return r;
}

// K1: s[gb][t][m*256+hw] = sum_d v[r][d]*e[t][d].
// grid 640 = (t-half, gb, m), 256 thr = 4 waves x 10 t, lanes own hw float4.
// Register-prefetch pipelined staging. __launch_bounds__(256,2): VGPR budget
// 256/wave so the a4[8]+acc[40] prefetch does NOT spill to scratch (R5 bug:
// default cap=64 VGPR -> 167 MB scratch writes, 5x slowdown).
__global__ __launch_bounds__(256, 2) void k1_gemm_s(const float* __restrict__ image,
                                                    const float* __restrict__ text,
                                                    float* __restrict__ ws) {
    __shared__ __align__(16) float A[32][260];   // [dd][hw]
    __shared__ __align__(16) float Et[32][52];   // [dd][w*12 + j]  (wave-padded)
    float* Sg = ws + OFF_S;
    int blk = blockIdx.x;
    int th = blk >= 320 ? 1 : 0;
    int rest = blk - th * 320;
    int m = rest & 7, gb = rest >> 3;
    int g = gb / 5;
    int tb = th * 40;                      // block covers t in [tb, tb+40)
    const float* cell = image + (size_t)(gb * 8 + m) * ND * NHW; // [d][hw]
    int tid = threadIdx.x;
    int lane = tid & 63;
    int w = __builtin_amdgcn_readfirstlane(tid >> 6); // 0..3; wave owns t = tb+w*10+j
    int hw4 = lane * 4;
    float4 acc[10];
#pragma unroll
    for (int j = 0; j < 10; ++j) acc[j] = make_float4(0.f, 0.f, 0.f, 0.f);
    float4 a4[8];
    float  e5[5];
#define K1_LOAD(D0)                                                          \
    {                                                                        \
        _Pragma("unroll")                                                    \
        for (int i = 0; i < 8; ++i) {                                        \
            int idx = tid + 256 * i;                                         \
            int dd = idx >> 6, h4 = (idx & 63) * 4;                          \
            a4[i] = *(const float4*)&cell[(size_t)((D0) + dd) * 256 + h4];   \
        }                                                                    \
        _Pragma("unroll")                                                    \
        for (int i = 0; i < 5; ++i) {                                        \
            int idx = tid + 256 * i;                                         \
            int dd = idx & 31, tcl = idx >> 5;                               \
            int t = tb + tcl; if (t > 74) t = 74;                            \
            e5[i] = text[((size_t)(g * 75 + t)) * 256 + (D0) + dd];          \
        }                                                                    \
    }
    K1_LOAD(0)
    for (int c = 0; c < 8; ++c) {
        __syncthreads();
#pragma unroll
        for (int i = 0; i < 8; ++i) {
            int idx = tid + 256 * i;
            int dd = idx >> 6, h4 = (idx & 63) * 4;
            *(float4*)&A[dd][h4] = a4[i];
        }
#pragma unroll
        for (int i = 0; i < 5; ++i) {
            int idx = tid + 256 * i;
            int dd = idx & 31, tcl = idx >> 5;
            int col = (tcl / 10) * 12 + (tcl % 10);
            Et[dd][col] = e5[i];
        }
        __syncthreads();
        if (c < 7) K1_LOAD((c + 1) * 32)
        for (int dd = 0; dd < 32; ++dd) {
            float4 av = *(const float4*)&A[dd][hw4];
            float4 e0 = *(const float4*)&Et[dd][w * 12];
            float4 e1 = *(const float4*)&Et[dd][w * 12 + 4];
            float2 e2 = *(const float2*)&Et[dd][w * 12 + 8];
            float ev[10] = {e0.x, e0.y, e0.z, e0.w, e1.x, e1.y, e1.z, e1.w, e2.x, e2.y};
#pragma unroll
            for (int j = 0; j < 10; ++j) {
                acc[j].x += av.x * ev[j]; acc[j].y += av.y * ev[j];
                acc[j].z += av.z * ev[j]; acc[j].w += av.w * ev[j];
            }
        }
    }
#undef K1_LOAD
#pragma unroll
    for (int j = 0; j < 10; ++j) {
        int t = tb + w * 10 + j;
        if (t < 75)
            *(float4*)&Sg[((size_t)gb * 75 + t) * 2048 + m * 256 + hw4] = acc[j];
    }
}

// K2: per-(r,seg) max/sumexp over the 15 tokens of the segment.
__global__ __launch_bounds__(256) void k2_rowstats(float* __restrict__ ws) {
    const float* Sg = ws + OFF_S;
    float* RMAX = ws + OFF_RMAX;
    float* RSUM = ws + OFF_RSUM;
    int blk = blockIdx.x;
    int m = blk & 7, gb = blk >> 3;
    int r = m * 256 + threadIdx.x;
    const float* base = Sg + (size_t)gb * 75 * 2048 + r;
    for (int seg = 0; seg < 5; ++seg) {
        float v[15]; float mx = -1e30f;
#pragma unroll
        for (int l = 0; l < 15; ++l) {
            v[l] = base[(size_t)(seg * 15 + l) * 2048];
            mx = fmaxf(mx, v[l]);
        }
        float sm = 0.f;
#pragma unroll
        for (int l = 0; l < 15; ++l) sm += __expf(v[l] - mx);
        RMAX[((size_t)gb * 5 + seg) * 2048 + r] = mx;
        RSUM[((size_t)gb * 5 + seg) * 2048 + r] = sm;
    }
}

// K3: per (gb,t) column over r=2048: colmax(s), colsum exp(s-cmax), colsum exp(s_nt);
// writes alpha (W) and per-m sums SD = sum_hw exp(p2). One pass over s.
__global__ __launch_bounds__(256) void k3_colstats(float* __restrict__ ws) {
    __shared__ float red[256];
    __shared__ float red8[8][256];
    const float* Sg = ws + OFF_S;
    const float* RMAX = ws + OFF_RMAX;
    const float* RSUM = ws + OFF_RSUM;
    float* W = ws + OFF_W;
    float* SD = ws + OFF_SD;
    int blk = blockIdx.x;           // t + 75*gb
    int t = blk % 75, gb = blk / 75;
    int seg = t / 15;
    int tid = threadIdx.x;
    const float* col = Sg + ((size_t)gb * 75 + t) * 2048;
    const float* rmx = RMAX + ((size_t)gb * 5 + seg) * 2048;
    const float* rsm = RSUM + ((size_t)gb * 5 + seg) * 2048;
    float sv[8], ent[8];
    float lmax = -1e30f, lsnt = 0.f;
#pragma unroll
    for (int k = 0; k < 8; ++k) {
        int r = tid + 256 * k;
        float s = col[r];
        sv[k] = s;
        float snt = 4.f * __expf(s - rmx[r]) / rsm[r];
        float e = __expf(snt);
        ent[k] = e;
        lsnt += e;
        lmax = fmaxf(lmax, s);
    }
    red[tid] = lmax; __syncthreads();
    for (int s2 = 128; s2 > 0; s2 >>= 1) {
        if (tid < s2) red[tid] = fmaxf(red[tid], red[tid + s2]);
        __syncthreads();
    }
    float cmax = red[0]; __syncthreads();
    float pe[8]; float lse = 0.f;
#pragma unroll
    for (int k = 0; k < 8; ++k) { pe[k] = __expf(sv[k] - cmax); lse += pe[k]; }
    float csum = bredsum(lse, red);
    float csnt = bredsum(lsnt, red);
    float inv = 1.f / csnt;
#pragma unroll
    for (int k = 0; k < 8; ++k)
        W[((size_t)gb * 75 + t) * 2048 + tid + 256 * k] = ent[k] * inv;
    float icsum = 1.f / csum;
#pragma unroll
    for (int k = 0; k < 8; ++k) red8[k][tid] = __expf(pe[k] * icsum);
    __syncthreads();
    for (int s2 = 128; s2 > 0; s2 >>= 1) {
        if (tid < s2) {
#pragma unroll
            for (int k2 = 0; k2 < 8; ++k2) red8[k2][tid] += red8[k2][tid + s2];
        }
        __syncthreads();
    }
    if (tid < 8) SD[((size_t)gb * 8 + tid) * 75 + t] = red8[tid][0];
}

// K4: v_tidal partials per m-cell: VTP[gb][m][t][d] = sum_{r in cell} alpha[r][t]*v[r][d].
// grid 640 = (t-half, gb, m), 256 thr = 4 waves x 10 t, lanes own d float4.
// Register-prefetch pipelined staging; __launch_bounds__(256,2) so v32[32]+acc[40]
// stay in VGPRs (no scratch spill).
__global__ __launch_bounds__(256, 2) void k4_vtidal(const float* __restrict__ image,
                                                    float* __restrict__ ws) {
    __shared__ __align__(16) float V[32][260];  // [rr][d]
    __shared__ __align__(16) float WtT[32][52]; // [rr][w*12 + j]
    const float* W = ws + OFF_W;
    float* VTP = ws + OFF_S; // s is dead; reuse
    int blk = blockIdx.x;
    int th = blk >= 320 ? 1 : 0;
    int rest = blk - th * 320;
    int m = rest & 7, gb = rest >> 3;
    int tb = th * 40;
    const float* cell = image + (size_t)(gb * 8 + m) * ND * NHW; // [d][hw]
    int tid = threadIdx.x;
    int lane = tid & 63;
    int w = __builtin_amdgcn_readfirstlane(tid >> 6); // 0..3; wave owns t = tb+w*10+j
    int d4 = lane * 4;
    float4 acc[10];
#pragma unroll
    for (int j = 0; j < 10; ++j) acc[j] = make_float4(0.f, 0.f, 0.f, 0.f);
    const float* wb = W + (size_t)gb * 75 * 2048 + m * 256;
    float v32[32];
    float w5[5];
#define K4_LOAD(RC)                                                          \
    {                                                                        \
        _Pragma("unroll")                                                    \
        for (int i = 0; i < 32; ++i) {                                       \
            int idx = tid + 256 * i;                                         \
            int rr = idx & 31, d = idx >> 5;                                 \
            v32[i] = cell[(size_t)d * 256 + (RC) * 32 + rr];                 \
        }                                                                    \
        _Pragma("unroll")                                                    \
        for (int i = 0; i < 5; ++i) {                                        \
            int idx = tid + 256 * i;                                         \
            int rr = idx & 31, tcl = idx >> 5;                               \
            int t = tb + tcl; if (t > 74) t = 74;                            \
            w5[i] = wb[(size_t)t * 2048 + (RC) * 32 + rr];                   \
        }                                                                    \
    }
    K4_LOAD(0)
    for (int rc = 0; rc < 8; ++rc) {
        __syncthreads();
#pragma unroll
        for (int i = 0; i < 32; ++i) {
            int idx = tid + 256 * i;
            int rr = idx & 31, d = idx >> 5;
            V[rr][d] = v32[i];
        }
#pragma unroll
        for (int i = 0; i < 5; ++i) {
            int idx = tid + 256 * i;
            int rr = idx & 31, tcl = idx >> 5;
            int col = (tcl / 10) * 12 + (tcl % 10);
            WtT[rr][col] = w5[i];
        }
        __syncthreads();
        if (rc < 7) K4_LOAD(rc + 1)
        for (int rr = 0; rr < 32; ++rr) {
            float4 vv = *(const float4*)&V[rr][d4];
            float4 q0 = *(const float4*)&WtT[rr][w * 12];
            float4 q1 = *(const float4*)&WtT[rr][w * 12 + 4];
            float2 q2 = *(const float2*)&WtT[rr][w * 12 + 8];
            float wv[10] = {q0.x, q0.y, q0.z, q0.w, q1.x, q1.y, q1.z, q1.w, q2.x, q2.y};
#pragma unroll
            for (int j = 0; j < 10; ++j) {
                acc[j].x += vv.x * wv[j]; acc[j].y += vv.y * wv[j];
                acc[j].z += vv.z * wv[j]; acc[j].w += vv.w * wv[j];
            }
        }
    }
#undef K4_LOAD
#pragma unroll
    for (int j = 0; j < 10; ++j) {
        int t = tb + w * 10 + j;
        if (t < 75)
            *(float4*)&VTP[((size_t)(gb * 8 + m) * 75 + t) * 256 + d4] = acc[j];
    }
}

// K5: v_tidal = sum_m VTP; logit[gb][t] = <vt/||vt||, e/||e||>.
__global__ __launch_bounds__(256) void k5_logit(const float* __restrict__ text,
                                                float* __restrict__ ws) {
    __shared__ float red[256];
    const float* VTP = ws + OFF_S;
    float* LG = ws + OFF_LG;
    int blk = blockIdx.x;
    int t = blk % 75, gb = blk / 75, g = gb / 5;
    int tid = threadIdx.x;
    float vt = 0.f;
#pragma unroll
    for (int m = 0; m < 8; ++m)
        vt += VTP[((size_t)(gb * 8 + m) * 75 + t) * 256 + tid];
    int seg = t / 15, l = t % 15;
    float ev = text[((size_t)(g * 5 + seg) * 15 + l) * 256 + tid];
    float nvt = bredsum(vt * vt, red);
    float nev = bredsum(ev * ev, red);
    float dot = bredsum(vt * ev, red);
    if (tid == 0)
        LG[gb * 75 + t] = dot / (fmaxf(sqrtf(nvt), 1e-12f) * fmaxf(sqrtf(nev), 1e-12f));
}

// K6: vns[gb][m][d] = sum_hw v[hw][d]/max(||v[hw]||,1e-12)
__global__ __launch_bounds__(256) void k6_vns(const float* __restrict__ image,
                                              float* __restrict__ ws) {
    __shared__ float A[32][257];
    __shared__ float rn[256];
    __shared__ float ps[256];
    float* VNS = ws + OFF_VNS;
    int blk = blockIdx.x;
    int m = blk & 7, gb = blk >> 3;
    const float* cell = image + (size_t)(gb * 8 + m) * ND * NHW;
    int tid = threadIdx.x;
    float nsq = 0.f;
    for (int d = 0; d < 256; ++d) {
        float v = cell[d * 256 + tid];
        nsq += v * v;
    }
    rn[tid] = 1.f / fmaxf(sqrtf(nsq), 1e-12f);
    int d_loc = tid & 31, sub = tid >> 5; // 8 subs x 32 d
    for (int d0 = 0; d0 < 256; d0 += 32) {
        __syncthreads();
#pragma unroll
        for (int i = 0; i < 32; ++i) A[i][tid] = cell[(d0 + i) * 256 + tid];
        __syncthreads();
        float partial = 0.f;
#pragma unroll
        for (int k = 0; k < 32; ++k) {
            int hw = sub + 8 * k;
            partial += A[d_loc][hw] * rn[hw];
        }
        ps[tid] = partial; __syncthreads();
        if (tid < 128) ps[tid] += ps[tid + 128];
        __syncthreads();
        if (tid < 64) ps[tid] += ps[tid + 64];
        __syncthreads();
        if (tid < 32)
            VNS[((size_t)gb * 8 + m) * 256 + d0 + tid] = ps[tid] + ps[tid + 32];
    }
}

// K7: beta from SD; em[s][d] = sum_l beta*e; logit2[gb][m][s] = <em/||em||, vns>/256.
__global__ __launch_bounds__(256) void k7_em(const float* __restrict__ text,
                                             float* __restrict__ ws) {
    __shared__ float red[256];
    __shared__ float sdv[75];
    __shared__ float segs[5];
    __shared__ float betas[5][15];
    const float* SD = ws + OFF_SD;
    const float* VNS = ws + OFF_VNS;
    float* BETA = ws + OFF_BETA;
    float* LG2 = ws + OFF_LG2;
    int blk = blockIdx.x;
    int m = blk & 7, gb = blk >> 3, g = gb / 5;
    int tid = threadIdx.x;
    if (tid < 75) sdv[tid] = SD[((size_t)gb * 8 + m) * 75 + tid];
    __syncthreads();
    if (tid < 5) {
        float s = 0.f;
        for (int l = 0; l < 15; ++l) s += sdv[tid * 15 + l];
        segs[tid] = s;
    }
    __syncthreads();
    if (tid < 75) {
        float b = sdv[tid] / segs[tid / 15];
        betas[tid / 15][tid % 15] = b;
        BETA[((size_t)gb * 8 + m) * 75 + tid] = b;
    }
    __syncthreads();
    float vns = VNS[((size_t)gb * 8 + m) * 256 + tid];
    for (int s = 0; s < 5; ++s) {
        float em = 0.f;
#pragma unroll
        for (int l = 0; l < 15; ++l)
            em += betas[s][l] * text[((size_t)(g * 5 + s) * 15 + l) * 256 + tid];
        float nem = bredsum(em * em, red);
        float dot = bredsum(em * vns, red);
        if (tid == 0)
            LG2[((size_t)gb * 8 + m) * 5 + s] =
                dot / fmaxf(sqrtf(nem), 1e-12f) * (1.f / 256.f);
        __syncthreads();
    }
}

// K8: per-g block assembly -> BLK[g]
__global__ __launch_bounds__(256) void k8_final(float* __restrict__ ws) {
    __shared__ float lsm[5][5];
    __shared__ float offsq[5][64];
    __shared__ float regs[5];
    const float* LG = ws + OFF_LG;
    const float* LG2 = ws + OFF_LG2;
    const float* BETA = ws + OFF_BETA;
    float* BLK = ws + OFF_BLK;
    int g = blockIdx.x;
    int tid = threadIdx.x;
    if (tid < 25) {
        int b = tid / 5, s = tid % 5;
        int gb = g * 5 + b;
        float s1 = 0.f;
        for (int l = 0; l < 15; ++l) s1 += expf(LG[gb * 75 + s * 15 + l]);
        float s2 = 0.f;
        for (int mm = 0; mm < 8; ++mm) s2 += expf(LG2[((size_t)gb * 8 + mm) * 5 + s]);
        float l1 = logf(powf(s1, 0.2f) + 1e-10f);
        float l2 = logf(powf(s2, 0.2f) + 1e-10f);
        lsm[b][s] = 10.f * (l1 + l2);
    }
    for (int p = tid; p < 320; p += 256) {
        int b = p >> 6, mn = p & 63, mm = mn >> 3, nn = mn & 7;
        int gb = g * 5 + b;
        const float* bm = BETA + ((size_t)gb * 8 + mm) * 75;
        const float* bn = BETA + ((size_t)gb * 8 + nn) * 75;
        float acc = 0.f;
        for (int t2 = 0; t2 < 75; ++t2) acc += bm[t2] * bn[t2];
        offsq[b][mn] = (mm == nn) ? 0.f : acc * acc;
    }
    __syncthreads();
    if (tid < 5) {
        float s = 0.f;
        for (int i = 0; i < 64; ++i) s += offsq[tid][i];
        regs[tid] = sqrtf(s);
    }
    __syncthreads();
    if (tid == 0) {
        float loss_reg = 0.f;
        for (int b = 0; b < 5; ++b) loss_reg += regs[b];
        loss_reg *= 0.2f;
        float pdq = 0.f, pqd = 0.f;
        for (int i = 0; i < 5; ++i) {
            float rsum = 0.f, csum = 0.f;
            for (int j = 0; j < 5; ++j) { rsum += lsm[i][j]; csum += lsm[j][i]; }
            float di = lsm[i][i];
            pdq += -logf(di / rsum + 1e-10f);
            pqd += -logf(di / csum + 1e-10f);
        }
        BLK[g] = (pdq + pqd) * 0.2f + loss_reg;
    }
}

__global__ void k9_out(const float* __restrict__ ws, float* __restrict__ out) {
    if (threadIdx.x == 0) {
        float s = 0.f;
        for (int g2 = 0; g2 < 8; ++g2) s += ws[OFF_BLK + g2];
        out[0] = s / 9.f;
    }
}

extern "C" void kernel_launch(void* const* d_in, const int* in_sizes, int n_in,
                              void* d_out, int out_size, void* d_ws, size_t ws_size,
                              hipStream_t stream) {
    const float* image = (const float*)d_in[0];
    const float* text  = (const float*)d_in[1];
    float* ws = (float*)d_ws;
    float* out = (float*)d_out;
    hipLaunchKernelGGL(k1_gemm_s,   dim3(640),  dim3(256), 0, stream, image, text, ws);
    hipLaunchKernelGGL(k2_rowstats, dim3(320),  dim3(256), 0, stream, ws);
    hipLaunchKernelGGL(k3_colstats, dim3(3000), dim3(256), 0, stream, ws);
    hipLaunchKernelGGL(k4_vtidal,   dim3(640),  dim3(256), 0, stream, image, ws);
    hipLaunchKernelGGL(k5_logit,    dim3(3000), dim3(256), 0, stream, text, ws);
    hipLaunchKernelGGL(k6_vns,      dim3(320),  dim3(256), 0, stream, image, ws);
    hipLaunchKernelGGL(k7_em,       dim3(320),  dim3(256), 0, stream, text, ws);
    hipLaunchKernelGGL(k8_final,    dim3(8),    dim3(256), 0, stream, ws);
    hipLaunchKernelGGL(k9_out,      dim3(1),    dim3(64),  0, stream, ws, out);
}

// Round 7
// 286.745 us; speedup vs baseline: 1.2089x; 1.2089x over previous
//
#include <hip/hip_runtime.h>
#include <hip/hip_bf16.h>
#include <math.h>

// Shapes (fixed per reference): B=40, M=8, D=256, H=16x16 -> HW=256, L=15
// Blocks: 8 blocks of 5 samples. Per block: R = 2048 regions, T = 75 tokens.
#define NG 8
#define NB5 5
#define NM 8
#define NHW 256
#define NR 2048
#define ND 256
#define NL 15
#define NT 75
#define NGB 40

// workspace layout (in floats)
#define OFF_S    0                         // s [gb][t][r], aliased later as VTP [gb][m][t][d]
#define SZ_S     (NGB*NT*NR)               // 6,144,000
#define OFF_W    (OFF_S + SZ_S)            // alpha [gb][t][r]
#define OFF_RMAX (OFF_W + SZ_S)            // [gb][seg][r]
#define SZ_RST   (NGB*5*NR)                // 409,600
#define OFF_RSUM (OFF_RMAX + SZ_RST)
#define OFF_SD   (OFF_RSUM + SZ_RST)       // [gb][m][t]
#define SZ_SD    (NGB*NM*NT)
#define OFF_VNS  (OFF_SD + SZ_SD)          // [gb][m][d]
#define SZ_VNS   (NGB*NM*ND)
#define OFF_LG   (OFF_VNS + SZ_VNS)        // logit [gb][t]
#define SZ_LG    (NGB*NT)
#define OFF_LG2  (OFF_LG + SZ_LG)          // logit2 [gb][m][s]
#define SZ_LG2   (NGB*NM*5)
#define OFF_BETA (OFF_LG2 + SZ_LG2)        // [gb][m][t]
#define SZ_BETA  (NGB*NM*NT)
#define OFF_BLK  (OFF_BETA + SZ_BETA)      // [g]

__device__ __forceinline__ float bredsum(float v, float* red) {
    int tid = threadIdx.x;
    red[tid] = v; __syncthreads();
    for (int s2 = 128; s2 > 0; s2 >>= 1) {
        if (tid < s2) red[tid] += red[tid + s2];
        __syncthreads();
    }
    float r = red[0]; __syncthreads();
    return r;
}

// K1: s[gb][t][m*256+hw] = sum_d v[r][d]*e[t][d].
// grid 640 = (t-half, gb, m), 256 thr = 4 waves x 10 t, lanes own hw float4.
// Prefetch lives in NAMED float4/float variables (p0..p7, e0..e4): SROA
// promotes named first-class values unconditionally, bypassing the
// AMDGPUPromoteAlloca budget that demoted the R5/R6 arrays to scratch
// (VGPR=64 + 174 MB scratch WRITE_SIZE -> 5x slowdown).
__global__ __launch_bounds__(256, 2) void k1_gemm_s(const float* __restrict__ image,
                                                    const float* __restrict__ text,
                                                    float* __restrict__ ws) {
    __shared__ __align__(16) float A[32][260];   // [dd][hw]
    __shared__ __align__(16) float Et[32][52];   // [dd][w*12 + j]  (wave-padded)
    float* Sg = ws + OFF_S;
    int blk = blockIdx.x;
    int th = blk >= 320 ? 1 : 0;
    int rest = blk - th * 320;
    int m = rest & 7, gb = rest >> 3;
    int g = gb / 5;
    int tb = th * 40;                      // block covers t in [tb, tb+40)
    const float* cell = image + (size_t)(gb * 8 + m) * ND * NHW; // [d][hw]
    int tid = threadIdx.x;
    int lane = tid & 63;
    int w = __builtin_amdgcn_readfirstlane(tid >> 6); // 0..3; wave owns t = tb+w*10+j
    int hw4 = lane * 4;
    int arow = tid >> 6;          // 0..3, A-row base (dd = arow + 4*i)
    int acol = (tid & 63) * 4;    // A col (float4)
    int edd  = tid & 31;          // Et dd
    int etc0 = tid >> 5;          // tcl = etc0 + 8*i
    float4 acc[10];
#pragma unroll
    for (int j = 0; j < 10; ++j) acc[j] = make_float4(0.f, 0.f, 0.f, 0.f);
    float4 p0, p1, p2, p3, p4, p5, p6, p7;
    float e0, e1, e2, e3, e4;
    const float* tbase = text + (size_t)g * 75 * 256;
#define K1_T(I) ((tb + etc0 + 8 * (I)) > 74 ? 74 : (tb + etc0 + 8 * (I)))
#define K1_LOAD(D0)                                                              \
    p0 = *(const float4*)&cell[(size_t)((D0) + arow +  0) * 256 + acol];         \
    p1 = *(const float4*)&cell[(size_t)((D0) + arow +  4) * 256 + acol];         \
    p2 = *(const float4*)&cell[(size_t)((D0) + arow +  8) * 256 + acol];         \
    p3 = *(const float4*)&cell[(size_t)((D0) + arow + 12) * 256 + acol];         \
    p4 = *(const float4*)&cell[(size_t)((D0) + arow + 16) * 256 + acol];         \
    p5 = *(const float4*)&cell[(size_t)((D0) + arow + 20) * 256 + acol];         \
    p6 = *(const float4*)&cell[(size_t)((D0) + arow + 24) * 256 + acol];         \
    p7 = *(const float4*)&cell[(size_t)((D0) + arow + 28) * 256 + acol];         \
    e0 = tbase[(size_t)K1_T(0) * 256 + (D0) + edd];                              \
    e1 = tbase[(size_t)K1_T(1) * 256 + (D0) + edd];                              \
    e2 = tbase[(size_t)K1_T(2) * 256 + (D0) + edd];                              \
    e3 = tbase[(size_t)K1_T(3) * 256 + (D0) + edd];                              \
    e4 = tbase[(size_t)K1_T(4) * 256 + (D0) + edd];
#define K1_ECOL(I) (((etc0 + 8 * (I)) / 10) * 12 + ((etc0 + 8 * (I)) % 10))
    K1_LOAD(0)
    for (int c = 0; c < 8; ++c) {
        __syncthreads();
        *(float4*)&A[arow +  0][acol] = p0;
        *(float4*)&A[arow +  4][acol] = p1;
        *(float4*)&A[arow +  8][acol] = p2;
        *(float4*)&A[arow + 12][acol] = p3;
        *(float4*)&A[arow + 16][acol] = p4;
        *(float4*)&A[arow + 20][acol] = p5;
        *(float4*)&A[arow + 24][acol] = p6;
        *(float4*)&A[arow + 28][acol] = p7;
        Et[edd][K1_ECOL(0)] = e0;
        Et[edd][K1_ECOL(1)] = e1;
        Et[edd][K1_ECOL(2)] = e2;
        Et[edd][K1_ECOL(3)] = e3;
        Et[edd][K1_ECOL(4)] = e4;
        __syncthreads();
        if (c < 7) { K1_LOAD((c + 1) * 32) }
        for (int dd = 0; dd < 32; ++dd) {
            float4 av = *(const float4*)&A[dd][hw4];
            float4 q0 = *(const float4*)&Et[dd][w * 12];
            float4 q1 = *(const float4*)&Et[dd][w * 12 + 4];
            float2 q2 = *(const float2*)&Et[dd][w * 12 + 8];
            float ev[10] = {q0.x, q0.y, q0.z, q0.w, q1.x, q1.y, q1.z, q1.w, q2.x, q2.y};
#pragma unroll
            for (int j = 0; j < 10; ++j) {
                acc[j].x += av.x * ev[j]; acc[j].y += av.y * ev[j];
                acc[j].z += av.z * ev[j]; acc[j].w += av.w * ev[j];
            }
        }
    }
#undef K1_LOAD
#undef K1_T
#undef K1_ECOL
#pragma unroll
    for (int j = 0; j < 10; ++j) {
        int t = tb + w * 10 + j;
        if (t < 75)
            *(float4*)&Sg[((size_t)gb * 75 + t) * 2048 + m * 256 + hw4] = acc[j];
    }
}

// K2: per-(r,seg) max/sumexp over the 15 tokens of the segment.
__global__ __launch_bounds__(256) void k2_rowstats(float* __restrict__ ws) {
    const float* Sg = ws + OFF_S;
    float* RMAX = ws + OFF_RMAX;
    float* RSUM = ws + OFF_RSUM;
    int blk = blockIdx.x;
    int m = blk & 7, gb = blk >> 3;
    int r = m * 256 + threadIdx.x;
    const float* base = Sg + (size_t)gb * 75 * 2048 + r;
    for (int seg = 0; seg < 5; ++seg) {
        float v[15]; float mx = -1e30f;
#pragma unroll
        for (int l = 0; l < 15; ++l) {
            v[l] = base[(size_t)(seg * 15 + l) * 2048];
            mx = fmaxf(mx, v[l]);
        }
        float sm = 0.f;
#pragma unroll
        for (int l = 0; l < 15; ++l) sm += __expf(v[l] - mx);
        RMAX[((size_t)gb * 5 + seg) * 2048 + r] = mx;
        RSUM[((size_t)gb * 5 + seg) * 2048 + r] = sm;
    }
}

// K3: per (gb,t) column over r=2048: colmax(s), colsum exp(s-cmax), colsum exp(s_nt);
// writes alpha (W) and per-m sums SD = sum_hw exp(p2). One pass over s.
__global__ __launch_bounds__(256) void k3_colstats(float* __restrict__ ws) {
    __shared__ float red[256];
    __shared__ float red8[8][256];
    const float* Sg = ws + OFF_S;
    const float* RMAX = ws + OFF_RMAX;
    const float* RSUM = ws + OFF_RSUM;
    float* W = ws + OFF_W;
    float* SD = ws + OFF_SD;
    int blk = blockIdx.x;           // t + 75*gb
    int t = blk % 75, gb = blk / 75;
    int seg = t / 15;
    int tid = threadIdx.x;
    const float* col = Sg + ((size_t)gb * 75 + t) * 2048;
    const float* rmx = RMAX + ((size_t)gb * 5 + seg) * 2048;
    const float* rsm = RSUM + ((size_t)gb * 5 + seg) * 2048;
    float sv[8], ent[8];
    float lmax = -1e30f, lsnt = 0.f;
#pragma unroll
    for (int k = 0; k < 8; ++k) {
        int r = tid + 256 * k;
        float s = col[r];
        sv[k] = s;
        float snt = 4.f * __expf(s - rmx[r]) / rsm[r];
        float e = __expf(snt);
        ent[k] = e;
        lsnt += e;
        lmax = fmaxf(lmax, s);
    }
    red[tid] = lmax; __syncthreads();
    for (int s2 = 128; s2 > 0; s2 >>= 1) {
        if (tid < s2) red[tid] = fmaxf(red[tid], red[tid + s2]);
        __syncthreads();
    }
    float cmax = red[0]; __syncthreads();
    float pe[8]; float lse = 0.f;
#pragma unroll
    for (int k = 0; k < 8; ++k) { pe[k] = __expf(sv[k] - cmax); lse += pe[k]; }
    float csum = bredsum(lse, red);
    float csnt = bredsum(lsnt, red);
    float inv = 1.f / csnt;
#pragma unroll
    for (int k = 0; k < 8; ++k)
        W[((size_t)gb * 75 + t) * 2048 + tid + 256 * k] = ent[k] * inv;
    float icsum = 1.f / csum;
#pragma unroll
    for (int k = 0; k < 8; ++k) red8[k][tid] = __expf(pe[k] * icsum);
    __syncthreads();
    for (int s2 = 128; s2 > 0; s2 >>= 1) {
        if (tid < s2) {
#pragma unroll
            for (int k2 = 0; k2 < 8; ++k2) red8[k2][tid] += red8[k2][tid + s2];
        }
        __syncthreads();
    }
    if (tid < 8) SD[((size_t)gb * 8 + tid) * 75 + t] = red8[tid][0];
}

// K4: v_tidal partials per m-cell: VTP[gb][m][t][d] = sum_{r in cell} alpha[r][t]*v[r][d].
// grid 640 = (t-half, gb, m), 256 thr = 4 waves x 10 t, lanes own d float4.
// Named-register prefetch (p0..p7 float4 along rr, w0..w4); V-transpose scatter
// writes are <=4-way bank conflicts on pad 260 (free-ish, ~200 slots/chunk).
__global__ __launch_bounds__(256, 2) void k4_vtidal(const float* __restrict__ image,
                                                    float* __restrict__ ws) {
    __shared__ __align__(16) float V[32][260];  // [rr][d]
    __shared__ __align__(16) float WtT[32][52]; // [rr][w*12 + j]
    const float* W = ws + OFF_W;
    float* VTP = ws + OFF_S; // s is dead; reuse
    int blk = blockIdx.x;
    int th = blk >= 320 ? 1 : 0;
    int rest = blk - th * 320;
    int m = rest & 7, gb = rest >> 3;
    int tb = th * 40;
    const float* cell = image + (size_t)(gb * 8 + m) * ND * NHW; // [d][hw]
    int tid = threadIdx.x;
    int lane = tid & 63;
    int w = __builtin_amdgcn_readfirstlane(tid >> 6); // 0..3; wave owns t = tb+w*10+j
    int d4 = lane * 4;
    int rr4  = (tid & 7) * 4;     // V rr base for this thread's float4
    int drow = tid >> 3;          // d = drow + 32*i
    int wrr  = tid & 31;          // WtT rr
    int wtc0 = tid >> 5;          // tcl = wtc0 + 8*i
    float4 acc[10];
#pragma unroll
    for (int j = 0; j < 10; ++j) acc[j] = make_float4(0.f, 0.f, 0.f, 0.f);
    const float* wb = W + (size_t)gb * 75 * 2048 + m * 256;
    float4 p0, p1, p2, p3, p4, p5, p6, p7;
    float w0, w1, w2, w3, w4;
#define K4_T(I) ((tb + wtc0 + 8 * (I)) > 74 ? 74 : (tb + wtc0 + 8 * (I)))
#define K4_LOAD(RC)                                                               \
    p0 = *(const float4*)&cell[(size_t)(drow +   0) * 256 + (RC) * 32 + rr4];     \
    p1 = *(const float4*)&cell[(size_t)(drow +  32) * 256 + (RC) * 32 + rr4];     \
    p2 = *(const float4*)&cell[(size_t)(drow +  64) * 256 + (RC) * 32 + rr4];     \
    p3 = *(const float4*)&cell[(size_t)(drow +  96) * 256 + (RC) * 32 + rr4];     \
    p4 = *(const float4*)&cell[(size_t)(drow + 128) * 256 + (RC) * 32 + rr4];     \
    p5 = *(const float4*)&cell[(size_t)(drow + 160) * 256 + (RC) * 32 + rr4];     \
    p6 = *(const float4*)&cell[(size_t)(drow + 192) * 256 + (RC) * 32 + rr4];     \
    p7 = *(const float4*)&cell[(size_t)(drow + 224) * 256 + (RC) * 32 + rr4];     \
    w0 = wb[(size_t)K4_T(0) * 2048 + (RC) * 32 + wrr];                            \
    w1 = wb[(size_t)K4_T(1) * 2048 + (RC) * 32 + wrr];                            \
    w2 = wb[(size_t)K4_T(2) * 2048 + (RC) * 32 + wrr];                            \
    w3 = wb[(size_t)K4_T(3) * 2048 + (RC) * 32 + wrr];                            \
    w4 = wb[(size_t)K4_T(4) * 2048 + (RC) * 32 + wrr];
#define K4_WCOL(I) (((wtc0 + 8 * (I)) / 10) * 12 + ((wtc0 + 8 * (I)) % 10))
#define K4_VST(P, DOFF)                                                           \
    V[rr4 + 0][drow + (DOFF)] = (P).x;                                            \
    V[rr4 + 1][drow + (DOFF)] = (P).y;                                            \
    V[rr4 + 2][drow + (DOFF)] = (P).z;                                            \
    V[rr4 + 3][drow + (DOFF)] = (P).w;
    K4_LOAD(0)
    for (int rc = 0; rc < 8; ++rc) {
        __syncthreads();
        K4_VST(p0,   0) K4_VST(p1,  32) K4_VST(p2,  64) K4_VST(p3,  96)
        K4_VST(p4, 128) K4_VST(p5, 160) K4_VST(p6, 192) K4_VST(p7, 224)
        WtT[wrr][K4_WCOL(0)] = w0;
        WtT[wrr][K4_WCOL(1)] = w1;
        WtT[wrr][K4_WCOL(2)] = w2;
        WtT[wrr][K4_WCOL(3)] = w3;
        WtT[wrr][K4_WCOL(4)] = w4;
        __syncthreads();
        if (rc < 7) { K4_LOAD(rc + 1) }
        for (int rr = 0; rr < 32; ++rr) {
            float4 vv = *(const float4*)&V[rr][d4];
            float4 q0 = *(const float4*)&WtT[rr][w * 12];
            float4 q1 = *(const float4*)&WtT[rr][w * 12 + 4];
            float2 q2 = *(const float2*)&WtT[rr][w * 12 + 8];
            float wv[10] = {q0.x, q0.y, q0.z, q0.w, q1.x, q1.y, q1.z, q1.w, q2.x, q2.y};
#pragma unroll
            for (int j = 0; j < 10; ++j) {
                acc[j].x += vv.x * wv[j]; acc[j].y += vv.y * wv[j];
                acc[j].z += vv.z * wv[j]; acc[j].w += vv.w * wv[j];
            }
        }
    }
#undef K4_LOAD
#undef K4_T
#undef K4_WCOL
#undef K4_VST
#pragma unroll
    for (int j = 0; j < 10; ++j) {
        int t = tb + w * 10 + j;
        if (t < 75)
            *(float4*)&VTP[((size_t)(gb * 8 + m) * 75 + t) * 256 + d4] = acc[j];
    }
}

// K5: v_tidal = sum_m VTP; logit[gb][t] = <vt/||vt||, e/||e||>.
__global__ __launch_bounds__(256) void k5_logit(const float* __restrict__ text,
                                                float* __restrict__ ws) {
    __shared__ float red[256];
    const float* VTP = ws + OFF_S;
    float* LG = ws + OFF_LG;
    int blk = blockIdx.x;
    int t = blk % 75, gb = blk / 75, g = gb / 5;
    int tid = threadIdx.x;
    float vt = 0.f;
#pragma unroll
    for (int m = 0; m < 8; ++m)
        vt += VTP[((size_t)(gb * 8 + m) * 75 + t) * 256 + tid];
    int seg = t / 15, l = t % 15;
    float ev = text[((size_t)(g * 5 + seg) * 15 + l) * 256 + tid];
    float nvt = bredsum(vt * vt, red);
    float nev = bredsum(ev * ev, red);
    float dot = bredsum(vt * ev, red);
    if (tid == 0)
        LG[gb * 75 + t] = dot / (fmaxf(sqrtf(nvt), 1e-12f) * fmaxf(sqrtf(nev), 1e-12f));
}

// K6: vns[gb][m][d] = sum_hw v[hw][d]/max(||v[hw]||,1e-12)
__global__ __launch_bounds__(256) void k6_vns(const float* __restrict__ image,
                                              float* __restrict__ ws) {
    __shared__ float A[32][257];
    __shared__ float rn[256];
    __shared__ float ps[256];
    float* VNS = ws + OFF_VNS;
    int blk = blockIdx.x;
    int m = blk & 7, gb = blk >> 3;
    const float* cell = image + (size_t)(gb * 8 + m) * ND * NHW;
    int tid = threadIdx.x;
    float nsq = 0.f;
    for (int d = 0; d < 256; ++d) {
        float v = cell[d * 256 + tid];
        nsq += v * v;
    }
    rn[tid] = 1.f / fmaxf(sqrtf(nsq), 1e-12f);
    int d_loc = tid & 31, sub = tid >> 5; // 8 subs x 32 d
    for (int d0 = 0; d0 < 256; d0 += 32) {
        __syncthreads();
#pragma unroll
        for (int i = 0; i < 32; ++i) A[i][tid] = cell[(d0 + i) * 256 + tid];
        __syncthreads();
        float partial = 0.f;
#pragma unroll
        for (int k = 0; k < 32; ++k) {
            int hw = sub + 8 * k;
            partial += A[d_loc][hw] * rn[hw];
        }
        ps[tid] = partial; __syncthreads();
        if (tid < 128) ps[tid] += ps[tid + 128];
        __syncthreads();
        if (tid < 64) ps[tid] += ps[tid + 64];
        __syncthreads();
        if (tid < 32)
            VNS[((size_t)gb * 8 + m) * 256 + d0 + tid] = ps[tid] + ps[tid + 32];
    }
}

// K7: beta from SD; em[s][d] = sum_l beta*e; logit2[gb][m][s] = <em/||em||, vns>/256.
__global__ __launch_bounds__(256) void k7_em(const float* __restrict__ text,
                                             float* __restrict__ ws) {
    __shared__ float red[256];
    __shared__ float sdv[75];
    __shared__ float segs[5];
    __shared__ float betas[5][15];
    const float* SD = ws + OFF_SD;
    const float* VNS = ws + OFF_VNS;
    float* BETA = ws + OFF_BETA;
    float* LG2 = ws + OFF_LG2;
    int blk = blockIdx.x;
    int m = blk & 7, gb = blk >> 3, g = gb / 5;
    int tid = threadIdx.x;
    if (tid < 75) sdv[tid] = SD[((size_t)gb * 8 + m) * 75 + tid];
    __syncthreads();
    if (tid < 5) {
        float s = 0.f;
        for (int l = 0; l < 15; ++l) s += sdv[tid * 15 + l];
        segs[tid] = s;
    }
    __syncthreads();
    if (tid < 75) {
        float b = sdv[tid] / segs[tid / 15];
        betas[tid / 15][tid % 15] = b;
        BETA[((size_t)gb * 8 + m) * 75 + tid] = b;
    }
    __syncthreads();
    float vns = VNS[((size_t)gb * 8 + m) * 256 + tid];
    for (int s = 0; s < 5; ++s) {
        float em = 0.f;
#pragma unroll
        for (int l = 0; l < 15; ++l)
            em += betas[s][l] * text[((size_t)(g * 5 + s) * 15 + l) * 256 + tid];
        float nem = bredsum(em * em, red);
        float dot = bredsum(em * vns, red);
        if (tid == 0)
            LG2[((size_t)gb * 8 + m) * 5 + s] =
                dot / fmaxf(sqrtf(nem), 1e-12f) * (1.f / 256.f);
        __syncthreads();
    }
}

// K8: per-g block assembly -> BLK[g]
__global__ __launch_bounds__(256) void k8_final(float* __restrict__ ws) {
    __shared__ float lsm[5][5];
    __shared__ float offsq[5][64];
    __shared__ float regs[5];
    const float* LG = ws + OFF_LG;
    const float* LG2 = ws + OFF_LG2;
    const float* BETA = ws + OFF_BETA;
    float* BLK = ws + OFF_BLK;
    int g = blockIdx.x;
    int tid = threadIdx.x;
    if (tid < 25) {
        int b = tid / 5, s = tid % 5;
        int gb = g * 5 + b;
        float s1 = 0.f;
        for (int l = 0; l < 15; ++l) s1 += expf(LG[gb * 75 + s * 15 + l]);
        float s2 = 0.f;
        for (int mm = 0; mm < 8; ++mm) s2 += expf(LG2[((size_t)gb * 8 + mm) * 5 + s]);
        float l1 = logf(powf(s1, 0.2f) + 1e-10f);
        float l2 = logf(powf(s2, 0.2f) + 1e-10f);
        lsm[b][s] = 10.f * (l1 + l2);
    }
    for (int p = tid; p < 320; p += 256) {
        int b = p >> 6, mn = p & 63, mm = mn >> 3, nn = mn & 7;
        int gb = g * 5 + b;
        const float* bm = BETA + ((size_t)gb * 8 + mm) * 75;
        const float* bn = BETA + ((size_t)gb * 8 + nn) * 75;
        float acc = 0.f;
        for (int t2 = 0; t2 < 75; ++t2) acc += bm[t2] * bn[t2];
        offsq[b][mn] = (mm == nn) ? 0.f : acc * acc;
    }
    __syncthreads();
    if (tid < 5) {
        float s = 0.f;
        for (int i = 0; i < 64; ++i) s += offsq[tid][i];
        regs[tid] = sqrtf(s);
    }
    __syncthreads();
    if (tid == 0) {
        float loss_reg = 0.f;
        for (int b = 0; b < 5; ++b) loss_reg += regs[b];
        loss_reg *= 0.2f;
        float pdq = 0.f, pqd = 0.f;
        for (int i = 0; i < 5; ++i) {
            float rsum = 0.f, csum = 0.f;
            for (int j = 0; j < 5; ++j) { rsum += lsm[i][j]; csum += lsm[j][i]; }
            float di = lsm[i][i];
            pdq += -logf(di / rsum + 1e-10f);
            pqd += -logf(di / csum + 1e-10f);
        }
        BLK[g] = (pdq + pqd) * 0.2f + loss_reg;
    }
}

__global__ void k9_out(const float* __restrict__ ws, float* __restrict__ out) {
    if (threadIdx.x == 0) {
        float s = 0.f;
        for (int g2 = 0; g2 < 8; ++g2) s += ws[OFF_BLK + g2];
        out[0] = s / 9.f;
    }
}

extern "C" void kernel_launch(void* const* d_in, const int* in_sizes, int n_in,
                              void* d_out, int out_size, void* d_ws, size_t ws_size,
                              hipStream_t stream) {
    const float* image = (const float*)d_in[0];
    const float* text  = (const float*)d_in[1];
    float* ws = (float*)d_ws;
    float* out = (float*)d_out;
    hipLaunchKernelGGL(k1_gemm_s,   dim3(640),  dim3(256), 0, stream, image, text, ws);
    hipLaunchKernelGGL(k2_rowstats, dim3(320),  dim3(256), 0, stream, ws);
    hipLaunchKernelGGL(k3_colstats, dim3(3000), dim3(256), 0, stream, ws);
    hipLaunchKernelGGL(k4_vtidal,   dim3(640),  dim3(256), 0, stream, image, ws);
    hipLaunchKernelGGL(k5_logit,    dim3(3000), dim3(256), 0, stream, text, ws);
    hipLaunchKernelGGL(k6_vns,      dim3(320),  dim3(256), 0, stream, image, ws);
    hipLaunchKernelGGL(k7_em,       dim3(320),  dim3(256), 0, stream, text, ws);
    hipLaunchKernelGGL(k8_final,    dim3(8),    dim3(256), 0, stream, ws);
    hipLaunchKernelGGL(k9_out,      dim3(1),    dim3(64),  0, stream, ws, out);
}